// Round 16
// baseline (573.799 us; speedup 1.0000x reference)
//
#include <hip/hip_runtime.h>
#include <hip/hip_bf16.h>
#include <hip/hip_fp16.h>
#include <hip/hip_cooperative_groups.h>

namespace cg = cooperative_groups;

#define IN_CH 128
#define OUT_CH 64
#define NBLK 512   // 2 blocks/CU co-resident (cooperative capacity-safe)
#define NTHR 256

typedef _Float16 hh2 __attribute__((ext_vector_type(2)));   // native half2 for v_dot2

// ---------------- hop phase body (wave per node, two 8-edge batches in flight) ----------------
template <int MODE>
__device__ __forceinline__ void hop_phase(const __half* __restrict__ zin,
                                          void* __restrict__ out,
                                          const unsigned short* __restrict__ eidx,
                                          const int* __restrict__ off,
                                          const float* __restrict__ dis,
                                          const float* __restrict__ bias,
                                          int n, int blk, int tid) {
    int lane = tid & 63;
    int wavei = tid >> 6;      // wave within block (4 waves)
    int grp = lane >> 3;       // edge slot in the octet
    int sub = lane & 7;        // 16B chunk of the 128B row
    int nGroups = (n + 3) >> 2;
    for (int gq = blk; gq < nGroups; gq += NBLK) {
        int v = gq * 4 + wavei;
        if (v >= n) continue;
        int s = off[v], e = off[v + 1];
        float a0 = 0.f, a1 = 0.f, a2 = 0.f, a3 = 0.f;
        float a4 = 0.f, a5 = 0.f, a6 = 0.f, a7 = 0.f;
        if (grp == 0) {        // self-loop term (z carries dis scaling)
            float4 raw = ((const float4*)(zin + (size_t)v * OUT_CH))[sub];
            const __half2* h2 = (const __half2*)&raw;
            float2 f0 = __half22float2(h2[0]), f1 = __half22float2(h2[1]);
            float2 f2 = __half22float2(h2[2]), f3 = __half22float2(h2[3]);
            a0 = f0.x; a1 = f0.y; a2 = f1.x; a3 = f1.y;
            a4 = f2.x; a5 = f2.y; a6 = f3.x; a7 = f3.y;
        }
        int i0 = s + grp, i1 = s + grp + 8;
        bool h0 = i0 < e, h1 = i1 < e;
        int r0 = h0 ? (int)eidx[i0] : 0;
        int r1 = h1 ? (int)eidx[i1] : 0;
        while (h0) {           // h1 implies h0
            int j0 = i0 + 16, j1 = i1 + 16;
            bool g0 = j0 < e, g1 = j1 < e;
            int q0 = g0 ? (int)eidx[j0] : 0;
            int q1 = g1 ? (int)eidx[j1] : 0;
            float4 rawA = make_float4(0.f, 0.f, 0.f, 0.f);
            float4 rawB = make_float4(0.f, 0.f, 0.f, 0.f);
            if (h0) rawA = ((const float4*)(zin + (size_t)r0 * OUT_CH))[sub];
            if (h1) rawB = ((const float4*)(zin + (size_t)r1 * OUT_CH))[sub];
            {
                const __half2* hA = (const __half2*)&rawA;
                float2 f0 = __half22float2(hA[0]), f1 = __half22float2(hA[1]);
                float2 f2 = __half22float2(hA[2]), f3 = __half22float2(hA[3]);
                a0 += f0.x; a1 += f0.y; a2 += f1.x; a3 += f1.y;
                a4 += f2.x; a5 += f2.y; a6 += f3.x; a7 += f3.y;
            }
            {
                const __half2* hB = (const __half2*)&rawB;
                float2 f0 = __half22float2(hB[0]), f1 = __half22float2(hB[1]);
                float2 f2 = __half22float2(hB[2]), f3 = __half22float2(hB[3]);
                a0 += f0.x; a1 += f0.y; a2 += f1.x; a3 += f1.y;
                a4 += f2.x; a5 += f2.y; a6 += f3.x; a7 += f3.y;
            }
            i0 = j0; i1 = j1; r0 = q0; r1 = q1; h0 = g0; h1 = g1;
        }
#pragma unroll
        for (int m = 8; m <= 32; m <<= 1) {
            a0 += __shfl_xor(a0, m, 64); a1 += __shfl_xor(a1, m, 64);
            a2 += __shfl_xor(a2, m, 64); a3 += __shfl_xor(a3, m, 64);
            a4 += __shfl_xor(a4, m, 64); a5 += __shfl_xor(a5, m, 64);
            a6 += __shfl_xor(a6, m, 64); a7 += __shfl_xor(a7, m, 64);
        }
        if (grp == 0) {
            float dv = dis[v];
            if (MODE == 0) {
                float sc = dv * dv;
                union { __half2 h[4]; float4 f; } u;
                u.h[0] = __floats2half2_rn(sc * a0, sc * a1);
                u.h[1] = __floats2half2_rn(sc * a2, sc * a3);
                u.h[2] = __floats2half2_rn(sc * a4, sc * a5);
                u.h[3] = __floats2half2_rn(sc * a6, sc * a7);
                ((float4*)((__half*)out + (size_t)v * OUT_CH))[sub] = u.f;
            } else {
                const float4* bp = (const float4*)(bias + sub * 8);
                float4 b0 = bp[0], b1 = bp[1];
                float* op = (float*)out + (size_t)v * OUT_CH + sub * 8;
                *(float4*)op = make_float4(fmaf(dv, a0, b0.x), fmaf(dv, a1, b0.y),
                                           fmaf(dv, a2, b0.z), fmaf(dv, a3, b0.w));
                *(float4*)(op + 4) = make_float4(fmaf(dv, a4, b1.x), fmaf(dv, a5, b1.y),
                                                 fmaf(dv, a6, b1.z), fmaf(dv, a7, b1.w));
            }
        }
    }
}

// ---------------- the whole SGC pipeline in one cooperative kernel ----------------
__global__ void __launch_bounds__(NTHR, 2) mega_kernel(
    const int* __restrict__ row, const int* __restrict__ col,
    const float* __restrict__ x, const float* __restrict__ W,
    const float* __restrict__ bias,
    int* __restrict__ blkcnt, int* __restrict__ totals,
    unsigned int* __restrict__ tmp, int* __restrict__ off,
    float* __restrict__ dis, unsigned short* __restrict__ eidx,
    __half* __restrict__ zA, __half* __restrict__ zB,
    float* __restrict__ out, int E, int n, int nbkt, int chunk) {
    cg::grid_group grid = cg::this_grid();
    __shared__ __align__(16) char smem[2 * 64 * 66 * sizeof(hh2)];   // 33792 B union
    int blk = blockIdx.x, tid = threadIdx.x;

    // ---- Phase 1: per-block 256-bucket histogram of col>>8 ----
    {
        int* h = (int*)smem;
        h[tid] = 0;
        __syncthreads();
        int s = blk * chunk, e = min(s + chunk, E);
        for (int i = s + tid; i < e; i += NTHR)
            atomicAdd(&h[col[i] >> 8], 1);                // LDS atomic
        __syncthreads();
        blkcnt[blk * 256 + tid] = h[tid];                 // coalesced
    }
    grid.sync();

    // ---- Phase 2: per-bucket exclusive scan over NBLK block counts ----
    if (blk < nbkt) {
        int* ps = (int*)smem;
        int i0 = (2 * tid) * 256 + blk, i1 = (2 * tid + 1) * 256 + blk;
        int a0 = blkcnt[i0], a1 = blkcnt[i1];
        int lsum = a0 + a1;
        ps[tid] = lsum;
        __syncthreads();
        for (int d = 1; d < 256; d <<= 1) {
            int t2 = 0;
            if (tid >= d) t2 = ps[tid - d];
            __syncthreads();
            if (tid >= d) ps[tid] += t2;
            __syncthreads();
        }
        int excl = ps[tid] - lsum;
        blkcnt[i0] = excl;
        blkcnt[i1] = excl + a0;
        if (tid == 255) totals[blk] = excl + lsum;
    }
    grid.sync();

    // ---- Phase 3: scatter edges into bucket-contiguous tmp ----
    {
        int* ps = (int*)smem;
        int* cur = ps + 256;
        int v = (tid < nbkt) ? totals[tid] : 0;
        ps[tid] = v;
        __syncthreads();
        for (int d = 1; d < 256; d <<= 1) {
            int t2 = 0;
            if (tid >= d) t2 = ps[tid - d];
            __syncthreads();
            if (tid >= d) ps[tid] += t2;
            __syncthreads();
        }
        cur[tid] = (ps[tid] - v) + blkcnt[blk * 256 + tid];
        __syncthreads();
        int s = blk * chunk, e = min(s + chunk, E);
        for (int i = s + tid; i < e; i += NTHR) {
            int c = col[i], r = row[i];
            int p = atomicAdd(&cur[c >> 8], 1);           // LDS atomic
            tmp[p] = ((unsigned)(c & 255) << 16) | (unsigned)r;
        }
    }
    grid.sync();

    // ---- Phase 4: per-bucket counting sort -> off/dis/eidx ----
    if (blk < nbkt) {
        int* bs = (int*)smem;
        int* cntl = bs + 256;
        int* sc = cntl + 256;
        int* posl = sc + 256;
        int v = (tid < nbkt) ? totals[tid] : 0;
        bs[tid] = v;
        __syncthreads();
        for (int d = 1; d < 256; d <<= 1) {
            int t2 = 0;
            if (tid >= d) t2 = bs[tid - d];
            __syncthreads();
            if (tid >= d) bs[tid] += t2;
            __syncthreads();
        }
        bs[tid] -= v;                                     // exclusive bucket bases
        cntl[tid] = 0;
        __syncthreads();
        int s = bs[blk], e = s + totals[blk];
        for (int i = s + tid; i < e; i += NTHR)
            atomicAdd(&cntl[tmp[i] >> 16], 1);            // LDS atomic
        __syncthreads();
        int c = cntl[tid];
        sc[tid] = c;
        __syncthreads();
        for (int d = 1; d < 256; d <<= 1) {
            int t2 = 0;
            if (tid >= d) t2 = sc[tid - d];
            __syncthreads();
            if (tid >= d) sc[tid] += t2;
            __syncthreads();
        }
        int excl = sc[tid] - c;
        int gid = (blk << 8) + tid;
        if (gid < n) {
            off[gid] = s + excl;
            dis[gid] = rsqrtf((float)(c + 1));            // +1 self-loop (gcn_norm)
        }
        posl[tid] = s + excl;
        if (blk == 0 && tid == 0) off[n] = E;
        __syncthreads();
        for (int i = s + tid; i < e; i += NTHR) {
            unsigned int w = tmp[i];
            int p = atomicAdd(&posl[w >> 16], 1);
            eidx[p] = (unsigned short)(w & 0xFFFFu);
        }
    }
    grid.sync();

    // ---- Phase 5: z = fp16( dis * (X @ W^T) ), half2 LDS + v_dot2 ----
    {
        hh2* Xs = (hh2*)smem;
        hh2* Ws = (hh2*)(smem + 64 * 66 * sizeof(hh2));
#pragma unroll
        for (int r = 0; r < 8; ++r) {                     // stage W once per block
            int f = tid + NTHR * r;
            int o = f >> 5, kq = f & 31;
            float4 w = ((const float4*)W)[f];
            Ws[o * 66 + kq * 2]     = hh2{(_Float16)w.x, (_Float16)w.y};
            Ws[o * 66 + kq * 2 + 1] = hh2{(_Float16)w.z, (_Float16)w.w};
        }
        int nTiles = (n + 63) >> 6;
        int tx = tid & 15, ty = tid >> 4;
        for (int tile = blk; tile < nTiles; tile += NBLK) {
            __syncthreads();                              // protect Xs reuse
            int m0 = tile * 64;
#pragma unroll
            for (int r = 0; r < 8; ++r) {                 // stage X tile
                int f = tid + NTHR * r;
                int node = f >> 5, kq = f & 31;
                int gv = min(m0 + node, n - 1);
                float4 xv = ((const float4*)(x + (size_t)gv * IN_CH))[kq];
                Xs[node * 66 + kq * 2]     = hh2{(_Float16)xv.x, (_Float16)xv.y};
                Xs[node * 66 + kq * 2 + 1] = hh2{(_Float16)xv.z, (_Float16)xv.w};
            }
            __syncthreads();
            float acc[4][4];
#pragma unroll
            for (int i = 0; i < 4; ++i)
#pragma unroll
                for (int j = 0; j < 4; ++j) acc[i][j] = 0.f;
#pragma unroll 4
            for (int kq = 0; kq < 32; ++kq) {
                hh2 xa0[4], xa1[4], wb0[4], wb1[4];
#pragma unroll
                for (int i = 0; i < 4; ++i) {
                    int base = (tx + 16 * i) * 66 + kq * 2;
                    xa0[i] = Xs[base]; xa1[i] = Xs[base + 1];
                }
#pragma unroll
                for (int j = 0; j < 4; ++j) {
                    int base = (ty * 4 + j) * 66 + kq * 2;
                    wb0[j] = Ws[base]; wb1[j] = Ws[base + 1];
                }
#pragma unroll
                for (int i = 0; i < 4; ++i)
#pragma unroll
                    for (int j = 0; j < 4; ++j) {
                        float s = acc[i][j];
                        s = __builtin_amdgcn_fdot2(xa0[i], wb0[j], s, false);
                        s = __builtin_amdgcn_fdot2(xa1[i], wb1[j], s, false);
                        acc[i][j] = s;
                    }
            }
#pragma unroll
            for (int i = 0; i < 4; ++i) {
                int v = m0 + tx + 16 * i;
                if (v < n) {
                    float dv = dis[v];
                    union { __half2 h[2]; float2 f; } u;
                    u.h[0] = __floats2half2_rn(dv * acc[i][0], dv * acc[i][1]);
                    u.h[1] = __floats2half2_rn(dv * acc[i][2], dv * acc[i][3]);
                    *(float2*)&zA[(size_t)v * OUT_CH + ty * 4] = u.f;
                }
            }
        }
    }
    grid.sync();

    // ---- Phase 6: hop 1 (zA -> zB, half) ----
    hop_phase<0>(zA, zB, eidx, off, dis, nullptr, n, blk, tid);
    grid.sync();

    // ---- Phase 7: hop 2 (zB -> out, float + bias) ----
    hop_phase<1>(zB, out, eidx, off, dis, bias, n, blk, tid);
}

extern "C" void kernel_launch(void* const* d_in, const int* in_sizes, int n_in,
                              void* d_out, int out_size, void* d_ws, size_t ws_size,
                              hipStream_t stream) {
    const int* ei = (const int*)d_in[1];
    int n = in_sizes[0] / IN_CH;   // 50000
    int E = in_sizes[1] / 2;       // 800000

    char* ws = (char*)d_ws;
    size_t o = 0;
    auto alloc = [&](size_t bytes) -> void* {
        void* p = ws + o;
        o += (bytes + 255) & ~(size_t)255;
        return p;
    };
    int nbkt = (n + 255) >> 8;          // 196
    int chunk = (E + NBLK - 1) / NBLK;  // 1563

    int*            blkcnt = (int*)alloc((size_t)NBLK * 256 * 4);
    int*            totals = (int*)alloc(256 * 4);
    unsigned int*   tmp    = (unsigned int*)alloc((size_t)E * 4);
    int*            off    = (int*)alloc((size_t)(n + 1) * 4);
    float*          dis    = (float*)alloc((size_t)n * 4);
    unsigned short* eidx   = (unsigned short*)alloc((size_t)E * 2);
    __half*         zA     = (__half*)alloc((size_t)n * OUT_CH * 2);
    __half*         zB     = (__half*)alloc((size_t)n * OUT_CH * 2);

    const int*   row_  = ei;            // edge_index[0] = source
    const int*   col_  = ei + E;        // edge_index[1] = target
    const float* x_    = (const float*)d_in[0];
    const float* W_    = (const float*)d_in[2];
    const float* b_    = (const float*)d_in[3];
    float*       out_  = (float*)d_out;

    void* kargs[] = {
        (void*)&row_, (void*)&col_, (void*)&x_, (void*)&W_, (void*)&b_,
        (void*)&blkcnt, (void*)&totals, (void*)&tmp, (void*)&off,
        (void*)&dis, (void*)&eidx, (void*)&zA, (void*)&zB,
        (void*)&out_, (void*)&E, (void*)&n, (void*)&nbkt, (void*)&chunk
    };
    hipLaunchCooperativeKernel((const void*)mega_kernel, dim3(NBLK), dim3(NTHR),
                               kargs, 0, stream);
}